// Round 5
// baseline (768.042 us; speedup 1.0000x reference)
//
#include <hip/hip_runtime.h>

typedef _Float16 half8 __attribute__((ext_vector_type(8)));
typedef float    floatx4 __attribute__((ext_vector_type(4)));
typedef unsigned short u16;

constexpr int Bn  = 8;
constexpr int Sq  = 2048;   // S1 == S2
constexpr int KD  = 512;    // K1_DIM == K2_DIM
constexpr int PKD = 256;
constexpr int AD  = 512;    // ATT_DIM
constexpr int DV  = 512;

// 16-byte async global->LDS DMA. LDS dest must be wave-uniform base + lane*16.
__device__ __forceinline__ void llds16(const void* g, void* l)
{
    __builtin_amdgcn_global_load_lds(
        (const __attribute__((address_space(1))) unsigned int*)g,
        (__attribute__((address_space(3))) unsigned int*)l, 16, 0, 0);
}

// ---------------------------------------------------------------------------
// transpose + cast f32 -> f16 (dual-source fold): out[j][i] = (f16) in[i][j]
// ---------------------------------------------------------------------------
__global__ __launch_bounds__(256)
void transpose_cast_k(const float* __restrict__ in0, const float* __restrict__ in1,
                      _Float16* __restrict__ out0, _Float16* __restrict__ out1,
                      int inRows, int inCols, long long bsIn, long long bsOut,
                      int zsplit)
{
    __shared__ float t[32][33];
    const int bz = blockIdx.z;
    const bool sel = (bz >= zsplit);
    const int b = sel ? bz - zsplit : bz;
    const float* in = (sel ? in1 : in0) + (long long)b * bsIn;
    _Float16* out = (sel ? out1 : out0) + (long long)b * bsOut;
    const int tx = threadIdx.x & 31;
    const int ty = threadIdx.x >> 5;     // 0..7
    const int c0 = blockIdx.x * 32;
    const int r0 = blockIdx.y * 32;
#pragma unroll
    for (int i = 0; i < 4; ++i)
        t[ty + 8*i][tx] = in[(long long)(r0 + ty + 8*i) * inCols + c0 + tx];
    __syncthreads();
#pragma unroll
    for (int i = 0; i < 4; ++i)
        out[(long long)(c0 + ty + 8*i) * inRows + r0 + tx] = (_Float16)t[tx][ty + 8*i];
}

// ---------------------------------------------------------------------------
// All four weight transposes in one launch. WT[n][k] = (f16) W[k][n].
// ---------------------------------------------------------------------------
__global__ __launch_bounds__(256)
void wT_all_k(const float* __restrict__ Wk1, const float* __restrict__ Wk2,
              const float* __restrict__ Wpk1, const float* __restrict__ Wpk2,
              _Float16* __restrict__ Tk1, _Float16* __restrict__ Tk2,
              _Float16* __restrict__ Tpk1, _Float16* __restrict__ Tpk2)
{
    const int z = blockIdx.z;
    const float* W; _Float16* T; int Krows;
    if      (z == 0) { W = Wk1;  T = Tk1;  Krows = KD; }
    else if (z == 1) { W = Wk2;  T = Tk2;  Krows = KD; }
    else if (z == 2) { W = Wpk1; T = Tpk1; Krows = KD + PKD; }
    else             { W = Wpk2; T = Tpk2; Krows = KD + PKD; }
    const int r0 = blockIdx.y * 32;          // k index
    if (r0 >= Krows) return;
    const int c0 = blockIdx.x * 32;          // n index (AD)
    __shared__ float t[32][33];
    const int tx = threadIdx.x & 31;
    const int ty = threadIdx.x >> 5;
#pragma unroll
    for (int i = 0; i < 4; ++i)
        t[ty + 8*i][tx] = W[(long long)(r0 + ty + 8*i) * AD + c0 + tx];
    __syncthreads();
#pragma unroll
    for (int i = 0; i < 4; ++i)
        T[(long long)(c0 + ty + 8*i) * Krows + r0 + tx] = (_Float16)t[tx][ty + 8*i];
}

// ---------------------------------------------------------------------------
// cast+concat f32 -> f16 (both sides): out[r][0..511]=x, out[r][512..767]=y.
// ---------------------------------------------------------------------------
__global__ __launch_bounds__(256)
void cast_cat_k(const float* __restrict__ x0, const float* __restrict__ y0,
                _Float16* __restrict__ o0,
                const float* __restrict__ x1, const float* __restrict__ y1,
                _Float16* __restrict__ o1)
{
    const bool sel = (blockIdx.z != 0);
    const float* x = sel ? x1 : x0;
    const float* y = sel ? y1 : y0;
    _Float16* out = sel ? o1 : o0;
    const int idx = blockIdx.x * 256 + threadIdx.x;
    const int e   = idx * 8;                 // < 16384*768 = 12.6M, fits int
    const int r   = e / 768;
    const int c   = e % 768;
    const float* src = (c < 512) ? (x + (long long)r * 512 + c)
                                 : (y + (long long)r * 256 + (c - 512));
    const floatx4 f0 = *(const floatx4*)(src);
    const floatx4 f1 = *(const floatx4*)(src + 4);
    half8 h;
#pragma unroll
    for (int j = 0; j < 4; ++j) { h[j] = (_Float16)f0[j]; h[4 + j] = (_Float16)f1[j]; }
    *(half8*)(out + (long long)e) = h;
}

// ---------------------------------------------------------------------------
// 128x128x32 fp16 MFMA GEMM (m97-style). Retained only for the !fast
// fallback (phase 4 reading f32 w).
// ---------------------------------------------------------------------------
template<bool A_F32, bool OUT_F16>
__global__ __launch_bounds__(256, 2)
void gemm_k(const void* __restrict__ A1v, const void* __restrict__ A2v, int Ksplit,
            int lda1, int lda2, long long bsA,
            const _Float16* __restrict__ Bm, int ldb, long long bsB,
            void* __restrict__ Cv, int ldc, long long bsC,
            const float* __restrict__ bias, int K)
{
    __shared__ __align__(16) unsigned char AsRaw[A_F32 ? 16384 : 8192]; // 128x32
    __shared__ __align__(16) unsigned char BsRaw[8192];                 // 128x32 f16

    const int tid  = threadIdx.x;
    const int lane = tid & 63;
    const int wave = tid >> 6;
    const int wm   = (wave >> 1) * 64;
    const int wn   = (wave & 1) * 64;
    const int fr   = lane & 15;
    const int fq   = lane >> 4;

    const int tm = blockIdx.y, tn = blockIdx.x, bz = blockIdx.z;
    const long long aRowBase = (long long)tm * 128;
    const long long bRowBase = (long long)tn * 128;
    const _Float16* Bbase = Bm + (long long)bz * bsB;

    floatx4 acc[4][4];
#pragma unroll
    for (int i = 0; i < 4; ++i)
#pragma unroll
        for (int j = 0; j < 4; ++j) acc[i][j] = (floatx4)0.0f;

    for (int k0 = 0; k0 < K; k0 += 32) {
        __syncthreads();

        if (A_F32) {
            const float* A1 = (const float*)A1v + (long long)bz * bsA;
            const float* A2 = (const float*)A2v;
#pragma unroll
            for (int is = 0; is < 4; ++is) {
                const int r  = (tid >> 3) + is * 32;
                const int ch = (tid & 7) ^ (r & 7);
                const int kk = k0 + ch * 4;
                const float* src = (kk < Ksplit)
                    ? A1 + (aRowBase + r) * lda1 + kk
                    : A2 + (aRowBase + r) * lda2 + (kk - Ksplit);
                llds16(src, AsRaw + tid * 16 + is * 4096);
            }
        } else {
            const _Float16* A1 = (const _Float16*)A1v + (long long)bz * bsA;
#pragma unroll
            for (int is = 0; is < 2; ++is) {
                const int r  = (tid >> 2) + is * 64;
                const int ch = (tid & 3) ^ (r & 3);
                llds16(A1 + (aRowBase + r) * lda1 + k0 + ch * 8,
                       AsRaw + tid * 16 + is * 4096);
            }
        }
#pragma unroll
        for (int is = 0; is < 2; ++is) {
            const int r  = (tid >> 2) + is * 64;
            const int ch = (tid & 3) ^ (r & 3);
            llds16(Bbase + (bRowBase + r) * ldb + k0 + ch * 8,
                   BsRaw + tid * 16 + is * 4096);
        }

        __syncthreads();

        half8 af[4], bf[4];
        if (A_F32) {
            const float* As32 = (const float*)AsRaw;
#pragma unroll
            for (int i = 0; i < 4; ++i) {
                const int r  = wm + i * 16 + fr;
                const int c0 = ((2 * fq) ^ (r & 7)) * 4;
                const int c1 = ((2 * fq + 1) ^ (r & 7)) * 4;
                floatx4 f0 = *(const floatx4*)(As32 + r * 32 + c0);
                floatx4 f1 = *(const floatx4*)(As32 + r * 32 + c1);
                half8 h;
#pragma unroll
                for (int j = 0; j < 4; ++j) {
                    h[j]     = (_Float16)f0[j];
                    h[4 + j] = (_Float16)f1[j];
                }
                af[i] = h;
            }
        } else {
            const _Float16* As16 = (const _Float16*)AsRaw;
#pragma unroll
            for (int i = 0; i < 4; ++i) {
                const int r  = wm + i * 16 + fr;
                const int ch = fq ^ (r & 3);
                af[i] = *(const half8*)(As16 + r * 32 + ch * 8);
            }
        }
        {
            const _Float16* Bs16 = (const _Float16*)BsRaw;
#pragma unroll
            for (int j = 0; j < 4; ++j) {
                const int r  = wn + j * 16 + fr;
                const int ch = fq ^ (r & 3);
                bf[j] = *(const half8*)(Bs16 + r * 32 + ch * 8);
            }
        }
#pragma unroll
        for (int i = 0; i < 4; ++i)
#pragma unroll
            for (int j = 0; j < 4; ++j)
                acc[i][j] = __builtin_amdgcn_mfma_f32_16x16x32_f16(af[i], bf[j], acc[i][j], 0, 0, 0);
    }

    const int crow0 = tm * 128 + wm + fq * 4;
    const int ccol0 = tn * 128 + wn + fr;
    if (OUT_F16) {
        _Float16* C = (_Float16*)Cv + (long long)bz * bsC;
#pragma unroll
        for (int i = 0; i < 4; ++i)
#pragma unroll
            for (int j = 0; j < 4; ++j) {
                const int col = ccol0 + j * 16;
                const float bv = bias[col];
#pragma unroll
                for (int r = 0; r < 4; ++r)
                    C[(long long)(crow0 + i*16 + r) * ldc + col] = (_Float16)(acc[i][j][r] + bv);
            }
    } else {
        float* C = (float*)Cv + (long long)bz * bsC;
#pragma unroll
        for (int i = 0; i < 4; ++i)
#pragma unroll
            for (int j = 0; j < 4; ++j) {
                const int col = ccol0 + j * 16;
#pragma unroll
                for (int r = 0; r < 4; ++r)
                    C[(long long)(crow0 + i*16 + r) * ldc + col] = acc[i][j][r];
            }
    }
}

// ---------------------------------------------------------------------------
// 256x256x(BK=64) f16 GEMM, 8-phase schedule. C = A[M][K] * B^T.
// Folded: z < zsplit uses (A0,B0,C0) batch z, else (A1,B1,C1) batch z-zsplit.
// OUT16: C f16 (score staging); else f32 final output (non-temporal stores).
// Generic grid (gx, gy, z); used at (8,8,16) for scores, (2,8,16) for o.
// ---------------------------------------------------------------------------
template<bool OUT16>
__global__ __launch_bounds__(512, 2)
void gemm256_k(const _Float16* __restrict__ A0, const _Float16* __restrict__ A1,
               const _Float16* __restrict__ B0, const _Float16* __restrict__ B1,
               void* __restrict__ C0v, void* __restrict__ C1v,
               long long bsA, int lda, long long bsB, int ldb,
               long long bsC, int ldc, int K, int zsplit)
{
    __shared__ __align__(16) _Float16 lds[65536];   // 2 bufs x (A 16384 + B 16384)

    const int gx   = gridDim.x, gy = gridDim.y;
    const int nwg  = gx * gy * gridDim.z;
    const int lin0 = (blockIdx.z * gy + blockIdx.y) * gx + blockIdx.x;
    const int cpx  = nwg >> 3;
    const int lin  = (lin0 & 7) * cpx + (lin0 >> 3);
    const int tn   = lin % gx;
    const int tmp2 = lin / gx;
    const int tm   = tmp2 % gy;
    const int bz   = tmp2 / gy;

    const bool sel = (bz >= zsplit);
    const int  bzl = sel ? (bz - zsplit) : bz;
    const _Float16* Am = sel ? A1 : A0;
    const _Float16* Bm = sel ? B1 : B0;

    const int tid  = threadIdx.x;
    const int lane = tid & 63;
    const int wave = tid >> 6;          // 0..7
    const int wm   = (wave >> 2) * 128; // 0 / 128
    const int wn   = (wave & 3) * 64;   // 0,64,128,192
    const int fr   = lane & 15;
    const int fq   = lane >> 4;

    const _Float16* Ab = Am + (long long)bzl * bsA + (long long)tm * 256 * lda;
    const _Float16* Bb = Bm + (long long)bzl * bsB + (long long)tn * 256 * ldb;

    const int sr = lane >> 3;           // sub-row within an 8-row stripe
    const int ch = (lane & 7) ^ sr;     // swizzled source chunk (row&7 == sr)
    const _Float16* srcA[2][2];
    const _Float16* srcB[2][2];
#pragma unroll
    for (int h = 0; h < 2; ++h)
#pragma unroll
        for (int l = 0; l < 2; ++l) {
            const int r = h * 128 + (wave * 2 + l) * 8 + sr;   // tile row 0..255
            srcA[h][l] = Ab + (long long)r * lda + ch * 8;
            srcB[h][l] = Bb + (long long)r * ldb + ch * 8;
        }

    auto stageA = [&](int kt, int buf) {
#pragma unroll
        for (int h = 0; h < 2; ++h)
#pragma unroll
            for (int l = 0; l < 2; ++l)
                llds16(srcA[h][l] + kt * 64,
                       lds + buf * 32768 + h * 8192 + (wave * 2 + l) * 512 + lane * 8);
    };
    auto stageB = [&](int kt, int buf) {
#pragma unroll
        for (int h = 0; h < 2; ++h)
#pragma unroll
            for (int l = 0; l < 2; ++l)
                llds16(srcB[h][l] + kt * 64,
                       lds + buf * 32768 + 16384 + h * 8192 + (wave * 2 + l) * 512 + lane * 8);
    };

    auto rdA = [&](int buf, int im, int kk) -> half8 {
        const int row = wm + im * 16 + fr;
        const int c   = (kk * 4 + fq) ^ (row & 7);
        return *(const half8*)(lds + buf * 32768 + row * 64 + c * 8);
    };
    auto rdB = [&](int buf, int jn, int kk) -> half8 {
        const int row = wn + jn * 16 + fr;
        const int c   = (kk * 4 + fq) ^ (row & 7);
        return *(const half8*)(lds + buf * 32768 + 16384 + row * 64 + c * 8);
    };

    floatx4 acc[8][4];
#pragma unroll
    for (int i = 0; i < 8; ++i)
#pragma unroll
        for (int j = 0; j < 4; ++j) acc[i][j] = (floatx4)0.0f;

    const int KT = K >> 6;              // K-tiles of 64

    stageA(0, 0);
    stageB(0, 0);
    __syncthreads();                    // gate: tile 0 visible

    for (int kt = 0; kt < KT; ++kt) {
        const int buf = kt & 1;
        half8 af[4][2], bf[2][2];
#pragma unroll
        for (int q = 0; q < 4; ++q) {
            const int nh = q >> 1;                    // 0,0,1,1
            const int mh = (q == 1 || q == 2) ? 1 : 0; // snake: 0,1,1,0
            if (q == 0 || q == 2) {
#pragma unroll
                for (int j = 0; j < 2; ++j)
#pragma unroll
                    for (int kk = 0; kk < 2; ++kk)
                        bf[j][kk] = rdB(buf, nh * 2 + j, kk);
            }
            if (q != 2) {                             // q2 reuses q1's A half
#pragma unroll
                for (int i = 0; i < 4; ++i)
#pragma unroll
                    for (int kk = 0; kk < 2; ++kk)
                        af[i][kk] = rdA(buf, mh * 4 + i, kk);
            }
            if (kt + 1 < KT) {                        // prefetch next K-tile early
                if (q == 0)      stageA(kt + 1, buf ^ 1);
                else if (q == 1) stageB(kt + 1, buf ^ 1);
            }
            __builtin_amdgcn_s_barrier();
            __builtin_amdgcn_s_setprio(1);
#pragma unroll
            for (int i = 0; i < 4; ++i)
#pragma unroll
                for (int j = 0; j < 2; ++j)
#pragma unroll
                    for (int kk = 0; kk < 2; ++kk)
                        acc[mh * 4 + i][nh * 2 + j] =
                            __builtin_amdgcn_mfma_f32_16x16x32_f16(
                                af[i][kk], bf[j][kk], acc[mh * 4 + i][nh * 2 + j], 0, 0, 0);
            __builtin_amdgcn_s_setprio(0);
            if (q < 3) __builtin_amdgcn_s_barrier();
        }
        __syncthreads();   // gate: flips buffers
    }

    // D layout (16x16): col = lane&15, row = (lane>>4)*4 + r
    const int crow0 = tm * 256 + wm + fq * 4;
    const int ccol0 = tn * 256 + wn + fr;
    if (OUT16) {
        _Float16* Cb = (_Float16*)(sel ? C1v : C0v) + (long long)bzl * bsC;
#pragma unroll
        for (int i = 0; i < 8; ++i)
#pragma unroll
            for (int j = 0; j < 4; ++j) {
                const long long base = (long long)(crow0 + i * 16) * ldc + ccol0 + j * 16;
#pragma unroll
                for (int r = 0; r < 4; ++r)
                    Cb[base + (long long)r * ldc] = (_Float16)acc[i][j][r];
            }
    } else {
        float* Cb = (float*)(sel ? C1v : C0v) + (long long)bzl * bsC;
#pragma unroll
        for (int i = 0; i < 8; ++i)
#pragma unroll
            for (int j = 0; j < 4; ++j) {
                const long long base = (long long)(crow0 + i * 16) * ldc + ccol0 + j * 16;
#pragma unroll
                for (int r = 0; r < 4; ++r)
                    __builtin_nontemporal_store(acc[i][j][r],
                        &Cb[base + (long long)r * ldc]);   // final output, never re-read
            }
    }
}

// ---------------------------------------------------------------------------
// All four projections in ONE launch, 3-buffer counted-vmcnt schedule.
// grid (4, 64, 4): pz = 0: cat1*WTk1->k1p, 1: cat2*WTk2->k2p,
//                  2: cat1*WTpk1->pk1,    3: cat2*WTpk2->pk2.
// ---------------------------------------------------------------------------
__global__ __launch_bounds__(512, 2)
void gemm_proj_k(const _Float16* __restrict__ Acat1, const _Float16* __restrict__ Acat2,
                 const _Float16* __restrict__ B0, const _Float16* __restrict__ B1,
                 const _Float16* __restrict__ B2, const _Float16* __restrict__ B3,
                 _Float16* __restrict__ C0, _Float16* __restrict__ C1,
                 _Float16* __restrict__ C2, _Float16* __restrict__ C3,
                 const float* __restrict__ bias0, const float* __restrict__ bias1,
                 const float* __restrict__ bias2, const float* __restrict__ bias3,
                 int K0, int K1)
{
    __shared__ __align__(16) _Float16 lds[73728];   // 3 bufs x 24576

    const int nwg  = 4 * 64 * 4;
    const int lin0 = (blockIdx.z * 64 + blockIdx.y) * 4 + blockIdx.x;
    const int cpx  = nwg >> 3;
    const int lin  = (lin0 & 7) * cpx + (lin0 >> 3);
    const int tn   = lin & 3;
    const int tm   = (lin >> 2) & 63;
    const int pz   = lin >> 8;          // 0..3

    const _Float16* Am = (pz & 1) ? Acat2 : Acat1;
    const _Float16* Bm; _Float16* Cm; const float* bias; int K;
    if      (pz == 0) { Bm = B0; Cm = C0; bias = bias0; K = K0; }
    else if (pz == 1) { Bm = B1; Cm = C1; bias = bias1; K = K0; }
    else if (pz == 2) { Bm = B2; Cm = C2; bias = bias2; K = K1; }
    else              { Bm = B3; Cm = C3; bias = bias3; K = K1; }
    const int lda = KD + PKD;           // cat leading dim
    const int ldb = K;                  // WT is [AD][K]
    const int ldc = AD;

    const int tid  = threadIdx.x;
    const int lane = tid & 63;
    const int wave = tid >> 6;
    const int wm   = (wave >> 2) * 128;
    const int wn   = (wave & 3) * 32;
    const int fr   = lane & 15;
    const int fq   = lane >> 4;

    const _Float16* Ab = Am + (long long)tm * 256 * lda;
    const _Float16* Bb = Bm + (long long)tn * 128 * ldb;

    const int sr = lane >> 3;
    const int ch = (lane & 7) ^ sr;
    const _Float16* srcA[2][2];
    const _Float16* srcB[2];
#pragma unroll
    for (int h = 0; h < 2; ++h)
#pragma unroll
        for (int l = 0; l < 2; ++l)
            srcA[h][l] = Ab + (long long)(h * 128 + (wave * 2 + l) * 8 + sr) * lda + ch * 8;
#pragma unroll
    for (int l = 0; l < 2; ++l)
        srcB[l] = Bb + (long long)((wave * 2 + l) * 8 + sr) * ldb + ch * 8;

    auto stageA = [&](int kt, int buf) {
#pragma unroll
        for (int h = 0; h < 2; ++h)
#pragma unroll
            for (int l = 0; l < 2; ++l)
                llds16(srcA[h][l] + kt * 64,
                       lds + buf * 24576 + h * 8192 + (wave * 2 + l) * 512 + lane * 8);
    };
    auto stageB = [&](int kt, int buf) {
#pragma unroll
        for (int l = 0; l < 2; ++l)
            llds16(srcB[l] + kt * 64,
                   lds + buf * 24576 + 16384 + (wave * 2 + l) * 512 + lane * 8);
    };

    auto rdA = [&](int buf, int im, int kk) -> half8 {
        const int row = wm + im * 16 + fr;
        const int c   = (kk * 4 + fq) ^ (row & 7);
        return *(const half8*)(lds + buf * 24576 + row * 64 + c * 8);
    };
    auto rdB = [&](int buf, int jn, int kk) -> half8 {
        const int row = wn + jn * 16 + fr;
        const int c   = (kk * 4 + fq) ^ (row & 7);
        return *(const half8*)(lds + buf * 24576 + 16384 + row * 64 + c * 8);
    };

    floatx4 acc[8][2];
#pragma unroll
    for (int i = 0; i < 8; ++i)
#pragma unroll
        for (int j = 0; j < 2; ++j) acc[i][j] = (floatx4)0.0f;

    const int KT = K >> 6;

    stageA(0, 0); stageB(0, 0);
    if (KT > 1) {
        stageA(1, 1); stageB(1, 1);
        asm volatile("s_waitcnt vmcnt(6)" ::: "memory");
    } else {
        asm volatile("s_waitcnt vmcnt(0)" ::: "memory");
    }
    __builtin_amdgcn_sched_barrier(0);
    __builtin_amdgcn_s_barrier();
    __builtin_amdgcn_sched_barrier(0);

    int bufR = 0, bufP = 2;
    for (int kt = 0; kt < KT; ++kt) {
        half8 afA[4][2], afB[4][2], bf0[2], bf1[2];
        const bool pf = (kt + 2 < KT);

#pragma unroll
        for (int kk = 0; kk < 2; ++kk) bf0[kk] = rdB(bufR, 0, kk);
#pragma unroll
        for (int i = 0; i < 4; ++i)
#pragma unroll
            for (int kk = 0; kk < 2; ++kk) afA[i][kk] = rdA(bufR, i, kk);
        if (pf) stageA(kt + 2, bufP);
        __builtin_amdgcn_s_barrier();
        __builtin_amdgcn_s_setprio(1);
#pragma unroll
        for (int i = 0; i < 4; ++i)
#pragma unroll
            for (int kk = 0; kk < 2; ++kk)
                acc[i][0] = __builtin_amdgcn_mfma_f32_16x16x32_f16(afA[i][kk], bf0[kk], acc[i][0], 0, 0, 0);
        __builtin_amdgcn_s_setprio(0);
        __builtin_amdgcn_s_barrier();

#pragma unroll
        for (int i = 0; i < 4; ++i)
#pragma unroll
            for (int kk = 0; kk < 2; ++kk) afB[i][kk] = rdA(bufR, 4 + i, kk);
        if (pf) stageB(kt + 2, bufP);
        __builtin_amdgcn_s_barrier();
        __builtin_amdgcn_s_setprio(1);
#pragma unroll
        for (int i = 0; i < 4; ++i)
#pragma unroll
            for (int kk = 0; kk < 2; ++kk)
                acc[4 + i][0] = __builtin_amdgcn_mfma_f32_16x16x32_f16(afB[i][kk], bf0[kk], acc[4 + i][0], 0, 0, 0);
        __builtin_amdgcn_s_setprio(0);
        __builtin_amdgcn_s_barrier();

#pragma unroll
        for (int kk = 0; kk < 2; ++kk) bf1[kk] = rdB(bufR, 1, kk);
        __builtin_amdgcn_s_barrier();
        __builtin_amdgcn_s_setprio(1);
#pragma unroll
        for (int i = 0; i < 4; ++i)
#pragma unroll
            for (int kk = 0; kk < 2; ++kk)
                acc[4 + i][1] = __builtin_amdgcn_mfma_f32_16x16x32_f16(afB[i][kk], bf1[kk], acc[4 + i][1], 0, 0, 0);
        __builtin_amdgcn_s_setprio(0);
        __builtin_amdgcn_s_barrier();

        __builtin_amdgcn_s_setprio(1);
#pragma unroll
        for (int i = 0; i < 4; ++i)
#pragma unroll
            for (int kk = 0; kk < 2; ++kk)
                acc[i][1] = __builtin_amdgcn_mfma_f32_16x16x32_f16(afA[i][kk], bf1[kk], acc[i][1], 0, 0, 0);
        __builtin_amdgcn_s_setprio(0);

        if (kt + 1 < KT) {
            if (pf) asm volatile("s_waitcnt vmcnt(6)" ::: "memory");
            else    asm volatile("s_waitcnt vmcnt(0)" ::: "memory");
            __builtin_amdgcn_sched_barrier(0);
            __builtin_amdgcn_s_barrier();
            __builtin_amdgcn_sched_barrier(0);
        }
        bufR = (bufR == 2) ? 0 : bufR + 1;
        bufP = (bufP == 2) ? 0 : bufP + 1;
    }

    const int crow0 = tm * 256 + wm + fq * 4;
    const int ccol0 = tn * 128 + wn + fr;
#pragma unroll
    for (int i = 0; i < 8; ++i)
#pragma unroll
        for (int j = 0; j < 2; ++j) {
            const int col = ccol0 + j * 16;
            const float bv = bias[col];
#pragma unroll
            for (int r = 0; r < 4; ++r)
                Cm[(long long)(crow0 + i * 16 + r) * ldc + col] = (_Float16)(acc[i][j][r] + bv);
        }
}

// ---------------------------------------------------------------------------
__device__ __forceinline__ int load_len(const int* __restrict__ p, int b)
{
    return (p[1] == 0) ? p[2 * b] : p[b];
}

// ---------------------------------------------------------------------------
// Masked softmax, both sides in one launch (z: 0 = w1 side, 1 = w2 side).
// F16IN: read f16 scores from wh, write f32 w (non-temporal; final output,
// never re-read) + f16 wh in place (re-read by phase 4 -> keep cacheable).
// ---------------------------------------------------------------------------
template<bool F16IN>
__global__ __launch_bounds__(256)
void softmax_mask_k(float* __restrict__ w1p, float* __restrict__ w2p,
                    _Float16* __restrict__ wh1, _Float16* __restrict__ wh2,
                    const int* __restrict__ len1, const int* __restrict__ len2)
{
    const int z = blockIdx.z;
    float* w = z ? w2p : w1p;
    _Float16* wh = z ? wh2 : wh1;
    const int* lenR = z ? len1 : len2;
    const int* lenC = z ? len2 : len1;

    const int b = blockIdx.y;
    const int r = blockIdx.x;
    const long long rowOff = ((long long)b * Sq + r) * (long long)Sq;
    float* row = w + rowOff;
    const int lr = load_len(lenR, b);
    const int lc = load_len(lenC, b);
    const bool rover = (r >= lr);
    const int tid  = threadIdx.x;
    const int lane = tid & 63;
    const int wave = tid >> 6;

    float v[8];
    if (F16IN) {
        const half8 hv = *(const half8*)(wh + rowOff + tid * 8);
#pragma unroll
        for (int j = 0; j < 8; ++j) v[j] = (float)hv[j];
    } else {
        const floatx4 x0 = *(const floatx4*)(row + tid * 8);
        const floatx4 x1 = *(const floatx4*)(row + tid * 8 + 4);
#pragma unroll
        for (int j = 0; j < 4; ++j) { v[j] = x0[j]; v[4 + j] = x1[j]; }
    }

    float m = -3.0e38f;
#pragma unroll
    for (int j = 0; j < 8; ++j) {
        const int c = tid * 8 + j;
        if (rover != (c >= lc)) v[j] = -__builtin_inff();
        m = fmaxf(m, v[j]);
    }
#pragma unroll
    for (int off = 32; off > 0; off >>= 1) m = fmaxf(m, __shfl_xor(m, off, 64));
    __shared__ float redm[4], reds[4];
    if (lane == 0) redm[wave] = m;
    __syncthreads();
    m = fmaxf(fmaxf(redm[0], redm[1]), fmaxf(redm[2], redm[3]));

    float s = 0.f;
#pragma unroll
    for (int j = 0; j < 8; ++j) { v[j] = __expf(v[j] - m); s += v[j]; }
#pragma unroll
    for (int off = 32; off > 0; off >>= 1) s += __shfl_xor(s, off, 64);
    if (lane == 0) reds[wave] = s;
    __syncthreads();
    s = reds[0] + reds[1] + reds[2] + reds[3];
    const float inv = 1.0f / s;   // row never fully masked (lengths in [S/2,S))

    floatx4 x0, x1;
#pragma unroll
    for (int j = 0; j < 4; ++j) { x0[j] = v[j] * inv; x1[j] = v[4 + j] * inv; }
    __builtin_nontemporal_store(x0, (floatx4*)(row + tid * 8));
    __builtin_nontemporal_store(x1, (floatx4*)(row + tid * 8 + 4));
    if (F16IN || wh != nullptr) {
        half8 h;
#pragma unroll
        for (int j = 0; j < 4; ++j) { h[j] = (_Float16)x0[j]; h[4 + j] = (_Float16)x1[j]; }
        *(half8*)(wh + rowOff + tid * 8) = h;
    }
}

// ---------------------------------------------------------------------------
extern "C" void kernel_launch(void* const* d_in, const int* in_sizes, int n_in,
                              void* d_out, int out_size, void* d_ws, size_t ws_size,
                              hipStream_t stream)
{
    (void)in_sizes; (void)n_in; (void)out_size;
    const float* k1    = (const float*)d_in[0];
    const float* k2    = (const float*)d_in[1];
    const float* pk1in = (const float*)d_in[2];
    const float* pk2in = (const float*)d_in[3];
    const float* v1    = (const float*)d_in[4];
    const float* v2    = (const float*)d_in[5];
    const float* W_k1  = (const float*)d_in[6];
    const float* b_k1  = (const float*)d_in[7];
    const float* W_k2  = (const float*)d_in[8];
    const float* b_k2  = (const float*)d_in[9];
    const float* W_pk1 = (const float*)d_in[10];
    const float* b_pk1 = (const float*)d_in[11];
    const float* W_pk2 = (const float*)d_in[12];
    const float* b_pk2 = (const float*)d_in[13];
    const int* len1 = (const int*)d_in[14];
    const int* len2 = (const int*)d_in[15];

    float* out = (float*)d_out;
    float* o1 = out;                                  // [Bn,Sq,DV]
    float* o2 = o1 + (long long)Bn * Sq * DV;         // [Bn,Sq,DV]
    float* w1 = o2 + (long long)Bn * Sq * DV;         // [Bn,Sq,Sq]
    float* w2 = w1 + (long long)Bn * Sq * Sq;         // [Bn,Sq,Sq]

    // fp16 intermediates live in the (dead until phase 4) o1/o2 regions.
    _Float16* k1p = (_Float16*)o1;                    // [Bn*Sq][AD]
    _Float16* k2p = k1p + (long long)Bn * Sq * AD;
    _Float16* pk1 = (_Float16*)o2;
    _Float16* pk2 = pk1 + (long long)Bn * Sq * AD;
    _Float16* cat1 = pk2 + (long long)Bn * Sq * AD;   // [Bn*Sq][KD+PKD] f16
    _Float16* cat2 = cat1 + (long long)Bn * Sq * (KD + PKD);

    _Float16* vT1   = (_Float16*)d_ws;                // [Bn][DV][Sq]
    _Float16* vT2   = vT1 + (long long)Bn * DV * Sq;
    _Float16* WTk1  = vT2 + (long long)Bn * DV * Sq;  // [AD][KD]
    _Float16* WTk2  = WTk1 + AD * KD;
    _Float16* WTpk1 = WTk2 + AD * KD;                 // [AD][KD+PKD]
    _Float16* WTpk2 = WTpk1 + AD * (KD + PKD);

    const unsigned long long fixedHalves =
        2ull * Bn * DV * Sq + 2ull * AD * KD + 2ull * AD * (KD + PKD);
    _Float16* w1h = (_Float16*)d_ws + fixedHalves;    // [Bn][Sq][Sq] f16
    _Float16* w2h = w1h + (long long)Bn * Sq * Sq;
    const bool fast =
        ws_size >= (fixedHalves + 2ull * Bn * Sq * Sq) * sizeof(_Float16);

    // ---- phase 0: weight transposes (1), v transposes (1), concat-casts (1)
    wT_all_k<<<dim3(AD/32, (KD+PKD)/32, 4), 256, 0, stream>>>(
        W_k1, W_k2, W_pk1, W_pk2, WTk1, WTk2, WTpk1, WTpk2);
    transpose_cast_k<<<dim3(DV/32, Sq/32, 2*Bn), 256, 0, stream>>>(
        v1, v2, vT1, vT2, Sq, DV, (long long)Sq*DV, (long long)Sq*DV, Bn);
    cast_cat_k<<<dim3((Bn*Sq*(KD+PKD))/(256*8), 1, 2), 256, 0, stream>>>(
        k1, pk1in, cat1, k2, pk2in, cat2);

    // ---- phase 1: all four projections in one launch ----
    gemm_proj_k<<<dim3(AD/128, (Bn*Sq)/256, 4), 512, 0, stream>>>(
        cat1, cat2,
        WTk1, WTk2, WTpk1, WTpk2,
        k1p, k2p, pk1, pk2,
        b_k1, b_k2, b_pk1, b_pk2,
        KD, KD + PKD);

    // ---- phase 2: both score GEMMs in one launch ----
    if (fast) {
        gemm256_k<true><<<dim3(Sq/256, Sq/256, 2*Bn), 512, 0, stream>>>(
            pk2, pk1, k1p, k2p, w1h, w2h,
            (long long)Sq*AD, AD, (long long)Sq*AD, AD,
            (long long)Sq*Sq, Sq, AD, Bn);
    } else {
        gemm256_k<false><<<dim3(Sq/256, Sq/256, 2*Bn), 512, 0, stream>>>(
            pk2, pk1, k1p, k2p, w1, w2,
            (long long)Sq*AD, AD, (long long)Sq*AD, AD,
            (long long)Sq*Sq, Sq, AD, Bn);
    }

    // ---- phase 3: masked softmax, both sides in one launch ----
    if (fast) {
        softmax_mask_k<true><<<dim3(Sq, Bn, 2), 256, 0, stream>>>(
            w1, w2, w1h, w2h, len1, len2);
    } else {
        softmax_mask_k<false><<<dim3(Sq, Bn, 2), 256, 0, stream>>>(
            w1, w2, nullptr, nullptr, len1, len2);
    }

    // ---- phase 4: o = w @ v via 256^2 kernel, grid (2,8,16) = 256 blocks ----
    if (fast) {
        gemm256_k<false><<<dim3(DV/256, Sq/256, 2*Bn), 512, 0, stream>>>(
            w1h, w2h, vT1, vT2, o1, o2,
            (long long)Sq*Sq, Sq, (long long)DV*Sq, Sq,
            (long long)Sq*DV, DV, Sq, Bn);
    } else {
        const dim3 gOut(DV/128, Sq/128, Bn);
        gemm_k<true, false><<<gOut, 256, 0, stream>>>(
            w1, w1, Sq, Sq, Sq, (long long)Sq*Sq,
            vT1, Sq, (long long)DV*Sq,
            o1, DV, (long long)Sq*DV, nullptr, Sq);
        gemm_k<true, false><<<gOut, 256, 0, stream>>>(
            w2, w2, Sq, Sq, Sq, (long long)Sq*Sq,
            vT2, Sq, (long long)DV*Sq,
            o2, DV, (long long)Sq*DV, nullptr, Sq);
    }
}